// Round 4
// baseline (871.025 us; speedup 1.0000x reference)
//
#include <hip/hip_runtime.h>

// B=512, V=256, W=64, H=64. Outputs: x_tilde_seq (64,512,256) fp32, h_seq (64,512,64) fp32.
// One block = 2 batches (bA, bA+256) interleaved per step. 512 threads, 1 block/CU.
// Register budget (256 = 128 VGPR + 128 AGPR unified): wihr[128] + E-slices[64] + ~10 misc.
// w_w, w_hh live in LDS (conflict-free read patterns); E lives in per-thread registers.

#define KLOG2E  1.4426950408889634f   // log2(e)
#define K2LOG2E 2.8853900817779268f   // 2*log2(e)

__device__ __forceinline__ float frcp(float x)  { return __builtin_amdgcn_rcpf(x); }
__device__ __forceinline__ float fexp2(float x) { return __builtin_amdgcn_exp2f(x); }
__device__ __forceinline__ float fsigmoid(float x) { return frcp(1.f + fexp2(-KLOG2E * x)); }
__device__ __forceinline__ float ftanh(float x) { return 1.f - 2.f * frcp(fexp2(K2LOG2E * x) + 1.f); }

// LDS layout (float offsets)
#define L_WW   0                    // w_w  [64][132]
#define L_WHH  8448                 // w_hh [256][68]
#define L_PS   25856                // union: U[64][68]=4352 (init) | psA[2048]+psB[2048] (loop)
#define L_PSA  25856
#define L_PSB  27904
#define L_XTA  30208                // x_tilde A [256]
#define L_XTB  30464
#define L_XSA  30720                // x_t stash A [256]
#define L_XSB  30976
#define L_EWA  31232                // e_w A [64]
#define L_EWB  31296
#define L_HCA  31360                // h||c A [128]
#define L_HCB  31488
#define L_BI   31616                // bias b_ih+b_hh [256]
#define L_WV   31872                // -2*w_v [64]
#define L_TOT  31936                // 127744 bytes

__global__ __launch_bounds__(512, 2) void enc_kernel(
    const float* __restrict__ x,     // (512,256,64)
    const float* __restrict__ w_ih,  // (256,256)
    const float* __restrict__ w_hh,  // (256,64)
    const float* __restrict__ b_ih,  // (256)
    const float* __restrict__ b_hh,  // (256)
    const float* __restrict__ w_v,   // (64)
    const float* __restrict__ w_w,   // (64,128)
    const float* __restrict__ b_w,   // (64)
    const float* __restrict__ w_u,   // (64,64)
    const float* __restrict__ b_u,   // (64)
    float* __restrict__ out_xt,      // (64,512,256)
    float* __restrict__ out_h)       // (64,512,64)
{
    extern __shared__ float lds[];
    float* wwL  = lds + L_WW;
    float* whhL = lds + L_WHH;
    float* U    = lds + L_PS;
    float* psA  = lds + L_PSA;  float* psB = lds + L_PSB;
    float* xtA  = lds + L_XTA;  float* xtB = lds + L_XTB;
    float* xsA  = lds + L_XSA;  float* xsB = lds + L_XSB;
    float* ewA  = lds + L_EWA;  float* ewB = lds + L_EWB;
    float* hcA  = lds + L_HCA;  float* hcB = lds + L_HCB;
    float* biasL= lds + L_BI;
    float* wv2L = lds + L_WV;

    const int tid  = threadIdx.x;
    const int lane = tid & 63;
    const int wvi  = tid >> 6;          // wave 0..7
    const int vg   = tid & 31;          // P2 v-group
    const int wq   = tid >> 5;          // P2 w-quad 0..15
    const int w8   = wvi*8 + (lane & 7);// P1 output w
    const int kg   = lane >> 3;         // P1 k-group 0..7
    const int bA   = blockIdx.x;
    const int bB   = blockIdx.x + 256;

    // ---- persistent per-thread gate weights: 4 outputs (jg+64q) x v-slice [32*sg,+32) ----
    float wihr[128];
    {
        const int jg = lane, sg = wvi;
#pragma unroll
        for (int jj = 0; jj < 4; ++jj) {
            const float4* g4 = (const float4*)(w_ih + (jg + 64*jj)*256 + sg*32);
#pragma unroll
            for (int i = 0; i < 8; ++i) {
                float4 v4 = g4[i];
                wihr[jj*32 + 4*i + 0] = v4.x; wihr[jj*32 + 4*i + 1] = v4.y;
                wihr[jj*32 + 4*i + 2] = v4.z; wihr[jj*32 + 4*i + 3] = v4.w;
            }
        }
    }
    const float bwr = b_w[w8];
    float Sv = 0.f;
#pragma unroll
    for (int wi = 0; wi < 64; ++wi) Sv += w_v[wi];   // uniform scalar loads
    const float bu_lane = b_u[lane];

    // ---- one-time LDS fills ----
    if (tid < 256) biasL[tid] = b_ih[tid] + b_hh[tid];
    if (tid < 64) wv2L[tid] = -2.f * w_v[tid];
    if (tid < 128) hcA[tid] = 0.f;
    else if (tid < 256) hcB[tid - 128] = 0.f;
    for (int i = tid; i < 8192; i += 512)            // w_w [64][132]
        wwL[(i >> 7)*132 + (i & 127)] = w_w[i];
    for (int i = tid; i < 16384; i += 512)           // w_hh [256][68]
        whhL[(i >> 6)*68 + (i & 63)] = w_hh[i];
    __syncthreads();

    // ---- E init: per-thread register slices via LDS quarter-staging ----
    // E[v][w] = exp(2*(x[b,v,:]@w_u[w,:] + b_u[w])); thread (vg,wq) holds
    // e?4[i] = E[vg+32i][wq*4..+4], i=0..8.
    float4 eA4[8], eB4[8];
#pragma unroll
    for (int bb = 0; bb < 2; ++bb) {
        const int b = bb ? bB : bA;
#pragma unroll
        for (int Q = 0; Q < 4; ++Q) {
            // producer: wave wvi covers vq = wvi*8..+8 (v = Q*64+vq); lane = w
#pragma unroll 1
            for (int half = 0; half < 2; ++half) {
                float4 wu_r[8];
#pragma unroll
                for (int i = 0; i < 8; ++i)
                    wu_r[i] = *(const float4*)&w_u[lane*64 + half*32 + 4*i];
#pragma unroll 2
                for (int vi = 0; vi < 8; ++vi) {
                    int vq = __builtin_amdgcn_readfirstlane(wvi*8 + vi);
                    const float4* xr = (const float4*)(x + b*16384 + (Q*64 + vq)*64 + half*32);
                    float acc = 0.f;
#pragma unroll
                    for (int i = 0; i < 8; ++i) {
                        float4 xx = xr[i]; float4 wu = wu_r[i];
                        acc += xx.x*wu.x + xx.y*wu.y + xx.z*wu.z + xx.w*wu.w;
                    }
                    if (half == 0) U[vq*68 + lane] = acc + bu_lane;
                    else           U[vq*68 + lane] += acc;
                }
            }
            __syncthreads();
            // consumer: rows vg and vg+32 of this quarter -> e regs 2Q, 2Q+1
            {
                float4 u0 = *(const float4*)&U[vg*68 + wq*4];
                float4 u1 = *(const float4*)&U[(vg + 32)*68 + wq*4];
                float4 r0, r1;
                r0.x = fexp2(K2LOG2E*u0.x); r0.y = fexp2(K2LOG2E*u0.y);
                r0.z = fexp2(K2LOG2E*u0.z); r0.w = fexp2(K2LOG2E*u0.w);
                r1.x = fexp2(K2LOG2E*u1.x); r1.y = fexp2(K2LOG2E*u1.y);
                r1.z = fexp2(K2LOG2E*u1.z); r1.w = fexp2(K2LOG2E*u1.w);
                if (bb == 0) { eA4[2*Q] = r0; eA4[2*Q+1] = r1; }
                else         { eB4[2*Q] = r0; eB4[2*Q+1] = r1; }
            }
            __syncthreads();
        }
    }

    // ---- x_t prefetch: thread -> (batch = tid>=256 ? B : A, j = tid&255) ----
    const int xj = tid & 255;
    const float* xrow = x + (tid < 256 ? bA : bB)*16384 + xj*64;
    float xnext = xrow[0];

    for (int t = 0; t < 64; ++t) {
        // ---- P1: stash x_t; wout partials; prefetch next x ----
        if (tid < 256) xsA[xj] = xnext; else xsB[xj] = xnext;
        {
            const int ksb = kg*16;
            float accA = 0.f, accB = 0.f;
#pragma unroll
            for (int i = 0; i < 4; ++i) {
                float4 w4 = *(const float4*)&wwL[w8*132 + ksb + 4*i];
                float4 hA = *(const float4*)&hcA[ksb + 4*i];
                float4 hB = *(const float4*)&hcB[ksb + 4*i];
                accA += hA.x*w4.x + hA.y*w4.y + hA.z*w4.z + hA.w*w4.w;
                accB += hB.x*w4.x + hB.y*w4.y + hB.z*w4.z + hB.w*w4.w;
            }
#pragma unroll
            for (int off = 8; off <= 32; off <<= 1) {
                accA += __shfl_xor(accA, off, 64);
                accB += __shfl_xor(accB, off, 64);
            }
            if (t < 63) xnext = xrow[t + 1];
            if (kg == 0)      ewA[w8] = fexp2(K2LOG2E * (accA + bwr));
            else if (kg == 1) ewB[w8] = fexp2(K2LOG2E * (accB + bwr));
        }
        __syncthreads();   // B1

        // ---- P2: score partials from register E. thread (vg, wq) ----
        {
            const float4 cA  = *(const float4*)&ewA[wq*4];
            const float4 cB  = *(const float4*)&ewB[wq*4];
            const float4 wv4 = *(const float4*)&wv2L[wq*4];
            float sA[8], sB[8];
#pragma unroll
            for (int i = 0; i < 8; ++i) {
                float4 e = eA4[i];
                sA[i] = wv4.x*frcp(e.x*cA.x + 1.f) + wv4.y*frcp(e.y*cA.y + 1.f)
                      + wv4.z*frcp(e.z*cA.z + 1.f) + wv4.w*frcp(e.w*cA.w + 1.f);
                e = eB4[i];
                sB[i] = wv4.x*frcp(e.x*cB.x + 1.f) + wv4.y*frcp(e.y*cB.y + 1.f)
                      + wv4.z*frcp(e.z*cB.z + 1.f) + wv4.w*frcp(e.w*cB.w + 1.f);
            }
            float* pdst = (lane < 32) ? psA : psB;
#pragma unroll
            for (int i = 0; i < 8; ++i) {
                sA[i] += __shfl_xor(sA[i], 32, 64);
                sB[i] += __shfl_xor(sB[i], 32, 64);
                pdst[wvi*256 + i*32 + vg] = (lane < 32) ? sA[i] : sB[i];
            }
        }
        __syncthreads();   // B2

        // ---- P3: softmax + x_tilde. wave0 = A, wave1 = B ----
        if (wvi < 2) {
            float* ps = wvi ? psB : psA;
            float* xs = wvi ? xsB : xsA;
            float* xt = wvi ? xtB : xtA;
            float s0 = Sv, s1 = Sv, s2 = Sv, s3 = Sv;
#pragma unroll
            for (int w = 0; w < 8; ++w) {
                s0 += ps[w*256 + lane      ];
                s1 += ps[w*256 + lane +  64];
                s2 += ps[w*256 + lane + 128];
                s3 += ps[w*256 + lane + 192];
            }
            float e0 = fexp2(KLOG2E*s0), e1 = fexp2(KLOG2E*s1);
            float e2 = fexp2(KLOG2E*s2), e3 = fexp2(KLOG2E*s3);
            float sum = (e0 + e1) + (e2 + e3);
#pragma unroll
            for (int off = 1; off <= 32; off <<= 1) sum += __shfl_xor(sum, off, 64);
            float r = frcp(sum);
            xt[lane      ] = e0*r*xs[lane      ];
            xt[lane +  64] = e1*r*xs[lane +  64];
            xt[lane + 128] = e2*r*xs[lane + 128];
            xt[lane + 192] = e3*r*xs[lane + 192];
        }
        __syncthreads();   // B3

        // ---- P4: gates partials (both batches) + cooperative out_xt store ----
        {
            // out_xt: all 512 threads store one element (coalesced 2x1KB)
            float xtv = (tid < 256) ? xtA[xj] : xtB[xj];
            out_xt[t*131072 + (tid < 256 ? bA : bB)*256 + xj] = xtv;

            const int sg = wvi, jg = lane;
            float a0=0.f,a1=0.f,a2=0.f,a3=0.f, c0=0.f,c1=0.f,c2=0.f,c3=0.f;
            const float4* xA4 = (const float4*)(xtA + sg*32);
            const float4* xB4 = (const float4*)(xtB + sg*32);
#pragma unroll
            for (int i = 0; i < 8; ++i) {
                float4 xa = xA4[i], xb = xB4[i];
                a0 += xa.x*wihr[   4*i] + xa.y*wihr[   4*i+1] + xa.z*wihr[   4*i+2] + xa.w*wihr[   4*i+3];
                a1 += xa.x*wihr[32+4*i] + xa.y*wihr[32+4*i+1] + xa.z*wihr[32+4*i+2] + xa.w*wihr[32+4*i+3];
                a2 += xa.x*wihr[64+4*i] + xa.y*wihr[64+4*i+1] + xa.z*wihr[64+4*i+2] + xa.w*wihr[64+4*i+3];
                a3 += xa.x*wihr[96+4*i] + xa.y*wihr[96+4*i+1] + xa.z*wihr[96+4*i+2] + xa.w*wihr[96+4*i+3];
                c0 += xb.x*wihr[   4*i] + xb.y*wihr[   4*i+1] + xb.z*wihr[   4*i+2] + xb.w*wihr[   4*i+3];
                c1 += xb.x*wihr[32+4*i] + xb.y*wihr[32+4*i+1] + xb.z*wihr[32+4*i+2] + xb.w*wihr[32+4*i+3];
                c2 += xb.x*wihr[64+4*i] + xb.y*wihr[64+4*i+1] + xb.z*wihr[64+4*i+2] + xb.w*wihr[64+4*i+3];
                c3 += xb.x*wihr[96+4*i] + xb.y*wihr[96+4*i+1] + xb.z*wihr[96+4*i+2] + xb.w*wihr[96+4*i+3];
            }
            // h-part: w_hh from LDS (rows jg+64q, k-slice sg*8..+8), reused for A and B
            float4 hA0 = *(const float4*)&hcA[sg*8];
            float4 hA1 = *(const float4*)&hcA[sg*8 + 4];
            float4 hB0 = *(const float4*)&hcB[sg*8];
            float4 hB1 = *(const float4*)&hcB[sg*8 + 4];
#pragma unroll
            for (int q = 0; q < 4; ++q) {
                float4 wh0 = *(const float4*)&whhL[(jg + 64*q)*68 + sg*8];
                float4 wh1 = *(const float4*)&whhL[(jg + 64*q)*68 + sg*8 + 4];
                float pa = hA0.x*wh0.x + hA0.y*wh0.y + hA0.z*wh0.z + hA0.w*wh0.w
                         + hA1.x*wh1.x + hA1.y*wh1.y + hA1.z*wh1.z + hA1.w*wh1.w;
                float pb = hB0.x*wh0.x + hB0.y*wh0.y + hB0.z*wh0.z + hB0.w*wh0.w
                         + hB1.x*wh1.x + hB1.y*wh1.y + hB1.z*wh1.z + hB1.w*wh1.w;
                if (q == 0) { a0 += pa; c0 += pb; }
                if (q == 1) { a1 += pa; c1 += pb; }
                if (q == 2) { a2 += pa; c2 += pb; }
                if (q == 3) { a3 += pa; c3 += pb; }
            }
            psA[sg*256 + jg      ] = a0;
            psA[sg*256 + jg +  64] = a1;
            psA[sg*256 + jg + 128] = a2;
            psA[sg*256 + jg + 192] = a3;
            psB[sg*256 + jg      ] = c0;
            psB[sg*256 + jg +  64] = c1;
            psB[sg*256 + jg + 128] = c2;
            psB[sg*256 + jg + 192] = c3;
        }
        __syncthreads();   // B4

        // ---- P5: LSTM cell. wave0 = A, wave1 = B ----
        if (wvi < 2) {
            float* ps = wvi ? psB : psA;
            float* hc = wvi ? hcB : hcA;
            float* oh = out_h + t*32768 + (wvi ? bB : bA)*64;
            const int k = lane;
            float gi = biasL[k], gf = biasL[64+k], gg = biasL[128+k], go = biasL[192+k];
#pragma unroll
            for (int s = 0; s < 8; ++s) {
                gi += ps[s*256 + k      ];
                gf += ps[s*256 + k +  64];
                gg += ps[s*256 + k + 128];
                go += ps[s*256 + k + 192];
            }
            gi = fsigmoid(gi); gf = fsigmoid(gf);
            gg = ftanh(gg);    go = fsigmoid(go);
            float cn = gf * hc[64 + k] + gi * gg;
            float hn = go * ftanh(cn);
            hc[k] = hn; hc[64 + k] = cn;
            oh[k] = hn;
        }
        __syncthreads();   // B5
    }
}

extern "C" void kernel_launch(void* const* d_in, const int* in_sizes, int n_in,
                              void* d_out, int out_size, void* d_ws, size_t ws_size,
                              hipStream_t stream) {
    const float* x    = (const float*)d_in[0];
    const float* w_ih = (const float*)d_in[1];
    const float* w_hh = (const float*)d_in[2];
    const float* b_ih = (const float*)d_in[3];
    const float* b_hh = (const float*)d_in[4];
    const float* w_v  = (const float*)d_in[5];
    const float* w_w  = (const float*)d_in[6];
    const float* b_w  = (const float*)d_in[7];
    const float* w_u  = (const float*)d_in[8];
    const float* b_u  = (const float*)d_in[9];

    float* out_xt = (float*)d_out;
    float* out_h  = out_xt + 64*512*256;

    const size_t shbytes = (size_t)L_TOT * sizeof(float);  // 127744 B
    hipFuncSetAttribute((const void*)enc_kernel,
                        hipFuncAttributeMaxDynamicSharedMemorySize, (int)shbytes);
    enc_kernel<<<dim3(256), dim3(512), shbytes, stream>>>(
        x, w_ih, w_hh, b_ih, b_hh, w_v, w_w, b_w, w_u, b_u, out_xt, out_h);
}

// Round 6
// 305.859 us; speedup vs baseline: 2.8478x; 2.8478x over previous
//
#include <hip/hip_runtime.h>

// B=512, V=256, W=64, H=64. Outputs: x_tilde_seq (64,512,256) fp32, h_seq (64,512,64) fp32.
// One block = 2 batches (bA, bA+256) interleaved per step; 512 threads, 1 block/CU.
// Persistent regs ~112/thread: w_ih as packed fp16 (64), w_hh fp32 (32), w_w slice (16).
// E = exp(2*(u_out+b_u)) in LDS (stride-68 rows, lane-consecutive b128 reads: conflict-free).

#define KLOG2E  1.4426950408889634f   // log2(e)
#define K2LOG2E 2.8853900817779268f   // 2*log2(e)

typedef _Float16 h2 __attribute__((ext_vector_type(2)));
union H2U { h2 h; unsigned u; };

__device__ __forceinline__ float frcp(float x)  { return __builtin_amdgcn_rcpf(x); }
__device__ __forceinline__ float fexp2(float x) { return __builtin_amdgcn_exp2f(x); }
__device__ __forceinline__ float fsigmoid(float x) { return frcp(1.f + fexp2(-KLOG2E * x)); }
__device__ __forceinline__ float ftanh(float x) { return 1.f - 2.f * frcp(fexp2(K2LOG2E * x) + 1.f); }

#if __has_builtin(__builtin_amdgcn_fdot2)
__device__ __forceinline__ float fdot2(h2 a, h2 b, float c) { return __builtin_amdgcn_fdot2(a, b, c, false); }
#else
__device__ __forceinline__ float fdot2(h2 a, h2 b, float c) { return c + (float)a.x*(float)b.x + (float)a.y*(float)b.y; }
#endif

__device__ __forceinline__ h2 pkrtz(float a, float b) {
#if __has_builtin(__builtin_amdgcn_cvt_pkrtz)
    return __builtin_bit_cast(h2, __builtin_amdgcn_cvt_pkrtz(a, b));
#else
    h2 r; r.x = (_Float16)a; r.y = (_Float16)b; return r;
#endif
}

// LDS layout (float offsets)
#define L_EA   0                    // E_A [256][68]
#define L_EB   17408                // E_B [256][68]
#define L_PSA  34816                // [2048]: P2 e(0..255)/e*x(256..511); P4 gate partials
#define L_PSB  36864                // [2048]
#define L_XTA  38912                // x_tilde A fp32 [256]
#define L_XTB  39168
#define L_XHA  39424                // x_tilde A half2-packed [128 uints]
#define L_XHB  39552
#define L_EWA  39680                // e_w A [64]
#define L_EWB  39744
#define L_HCA  39808                // h||c A [128]
#define L_HCB  39936
#define L_BI   40064                // bias b_ih+b_hh [256]
#define L_WV   40320                // -2*w_v [64]
#define L_TOT  40384                // 161536 bytes

__global__ __launch_bounds__(512, 2) void enc_kernel(
    const float* __restrict__ x,     // (512,256,64)
    const float* __restrict__ w_ih,  // (256,256)
    const float* __restrict__ w_hh,  // (256,64)
    const float* __restrict__ b_ih,  // (256)
    const float* __restrict__ b_hh,  // (256)
    const float* __restrict__ w_v,   // (64)
    const float* __restrict__ w_w,   // (64,128)
    const float* __restrict__ b_w,   // (64)
    const float* __restrict__ w_u,   // (64,64)
    const float* __restrict__ b_u,   // (64)
    float* __restrict__ out_xt,      // (64,512,256)
    float* __restrict__ out_h)       // (64,512,64)
{
    extern __shared__ float lds[];
    float* EA  = lds + L_EA;   float* EB  = lds + L_EB;
    float* psA = lds + L_PSA;  float* psB = lds + L_PSB;
    float* xtA = lds + L_XTA;  float* xtB = lds + L_XTB;
    float* xhA = lds + L_XHA;  float* xhB = lds + L_XHB;
    float* ewA = lds + L_EWA;  float* ewB = lds + L_EWB;
    float* hcA = lds + L_HCA;  float* hcB = lds + L_HCB;
    float* biasL = lds + L_BI;
    float* wv2L  = lds + L_WV;

    const int tid  = threadIdx.x;
    const int lane = tid & 63;
    const int wvi  = tid >> 6;            // wave 0..7
    const int bA   = blockIdx.x;
    const int bB   = blockIdx.x + 256;

    // ---- persistent per-thread weights ----
    // gates: thread (jg=lane, sg=wvi) -> rows jg+64*jj over v-slice [32*sg,+32), fp16-packed
    h2    wihr2[64];
    float whhr[32];
    {
        const int jg = lane, sg = wvi;
#pragma unroll
        for (int jj = 0; jj < 4; ++jj) {
            const float4* g4 = (const float4*)(w_ih + (jg + 64*jj)*256 + sg*32);
#pragma unroll
            for (int i = 0; i < 8; ++i) {
                float4 v4 = g4[i];
                wihr2[jj*16 + 2*i + 0] = pkrtz(v4.x, v4.y);
                wihr2[jj*16 + 2*i + 1] = pkrtz(v4.z, v4.w);
            }
            const float4* h4 = (const float4*)(w_hh + (jg + 64*jj)*64 + sg*8);
            float4 u0 = h4[0], u1 = h4[1];
            whhr[jj*8 + 0] = u0.x; whhr[jj*8 + 1] = u0.y;
            whhr[jj*8 + 2] = u0.z; whhr[jj*8 + 3] = u0.w;
            whhr[jj*8 + 4] = u1.x; whhr[jj*8 + 5] = u1.y;
            whhr[jj*8 + 6] = u1.z; whhr[jj*8 + 7] = u1.w;
        }
    }
    // wout: thread (w8 = wvi*8+(lane&7), kg = lane>>3) covers k = kg*4 + 32m (m=0..3)
    const int w8 = wvi*8 + (lane & 7);
    const int kg = lane >> 3;
    float4 www4[4];
#pragma unroll
    for (int m = 0; m < 4; ++m)
        www4[m] = *(const float4*)&w_w[w8*128 + kg*4 + 32*m];
    const float bwr = b_w[w8];
    float Sv = 0.f;
#pragma unroll
    for (int wi = 0; wi < 64; ++wi) Sv += w_v[wi];   // uniform scalar loads
    const float bu_lane = b_u[lane];

    // ---- one-time LDS fills ----
    if (tid < 256) biasL[tid] = b_ih[tid] + b_hh[tid];
    if (tid < 64) wv2L[tid] = -2.f * w_v[tid];
    if (tid < 128) hcA[tid] = 0.f;
    else if (tid < 256) hcB[tid - 128] = 0.f;

    // ---- E init: E[v][w] = exp(2*(x[b,v,:]@w_u[w,:] + b_u[w])), wave covers 32 rows ----
#pragma unroll 1
    for (int bb = 0; bb < 2; ++bb) {
        float* E = bb ? EB : EA;
        const int b = bb ? bB : bA;
#pragma unroll 1
        for (int half = 0; half < 2; ++half) {
            float4 wu_r[8];
#pragma unroll
            for (int i = 0; i < 8; ++i)
                wu_r[i] = *(const float4*)&w_u[lane*64 + half*32 + 4*i];
            const float* xb = x + b*16384 + half*32;
#pragma unroll 2
            for (int vi = 0; vi < 32; ++vi) {
                int v = __builtin_amdgcn_readfirstlane(wvi*32 + vi);
                const float4* xr = (const float4*)(xb + v*64);
                float acc = 0.f;
#pragma unroll
                for (int i = 0; i < 8; ++i) {
                    float4 xx = xr[i]; float4 wu = wu_r[i];
                    acc += xx.x*wu.x + xx.y*wu.y + xx.z*wu.z + xx.w*wu.w;
                }
                if (half == 0) E[v*68 + lane] = acc + bu_lane;
                else           E[v*68 + lane] = fexp2(K2LOG2E * (E[v*68 + lane] + acc));
            }
        }
    }
    __syncthreads();

    // ---- P2 thread identity: (j = tid&255, batch = tid>>8); x_t lives in a register ----
    const int  xj   = tid & 255;
    const int  bsel = tid >> 8;
    const float* xrow = x + (bsel ? bB : bA)*16384 + xj*64;
    float*       psX  = bsel ? psB : psA;
    const float* Erow = (bsel ? EB : EA) + xj*68;
    const float* ewX  = bsel ? ewB : ewA;
    float xcur = xrow[0];

    for (int t = 0; t < 64; ++t) {
        // ---- P1: wout partials (interleaved k-slices; conflict-free hc reads) ----
        {
            float accA = 0.f, accB = 0.f;
#pragma unroll
            for (int m = 0; m < 4; ++m) {
                float4 w4 = www4[m];
                float4 hA = *(const float4*)&hcA[kg*4 + 32*m];
                float4 hB = *(const float4*)&hcB[kg*4 + 32*m];
                accA += hA.x*w4.x + hA.y*w4.y + hA.z*w4.z + hA.w*w4.w;
                accB += hB.x*w4.x + hB.y*w4.y + hB.z*w4.z + hB.w*w4.w;
            }
#pragma unroll
            for (int off = 8; off <= 32; off <<= 1) {
                accA += __shfl_xor(accA, off, 64);
                accB += __shfl_xor(accB, off, 64);
            }
            if (kg == 0)      ewA[w8] = fexp2(K2LOG2E * (accA + bwr));
            else if (kg == 1) ewB[w8] = fexp2(K2LOG2E * (accB + bwr));
        }
        float xnxt = (t < 63) ? xrow[t + 1] : 0.f;   // prefetch; latency spans B1+P2
        __syncthreads();   // B1

        // ---- P2: full score per thread -> e, e*x_t ----
        {
            float acc = Sv;
#pragma unroll
            for (int q = 0; q < 16; ++q) {
                float4 e4 = *(const float4*)&Erow[4*q];
                float4 c4 = *(const float4*)&ewX[4*q];
                float4 v4 = *(const float4*)&wv2L[4*q];
                acc += v4.x * frcp(e4.x*c4.x + 1.f);
                acc += v4.y * frcp(e4.y*c4.y + 1.f);
                acc += v4.z * frcp(e4.z*c4.z + 1.f);
                acc += v4.w * frcp(e4.w*c4.w + 1.f);
            }
            float e = fexp2(KLOG2E * acc);   // |score| <= sum|w_v| ~ 2.6: no max-subtract
            psX[xj]       = e;
            psX[256 + xj] = e * xcur;
        }
        xcur = xnxt;
        __syncthreads();   // B2

        // ---- P3: softmax + x_tilde (wave0 = A, wave1 = B); 4 consecutive j per lane ----
        if (wvi < 2) {
            float* ps = wvi ? psB : psA;
            float* xt = wvi ? xtB : xtA;
            unsigned* xh = (unsigned*)(wvi ? xhB : xhA);
            float4 ev = *(const float4*)&ps[4*lane];
            float4 ex = *(const float4*)&ps[256 + 4*lane];
            float sum = (ev.x + ev.y) + (ev.z + ev.w);
#pragma unroll
            for (int off = 1; off <= 32; off <<= 1) sum += __shfl_xor(sum, off, 64);
            float r = frcp(sum);
            float4 xo;
            xo.x = ex.x*r; xo.y = ex.y*r; xo.z = ex.z*r; xo.w = ex.w*r;
            *(float4*)&xt[4*lane] = xo;
            H2U p0, p1;
            p0.h = pkrtz(xo.x, xo.y);
            p1.h = pkrtz(xo.z, xo.w);
            xh[2*lane]     = p0.u;
            xh[2*lane + 1] = p1.u;
        }
        __syncthreads();   // B3

        // ---- P4: out_xt store + gates partials via v_dot2_f32_f16 ----
        {
            float xtv = bsel ? xtB[xj] : xtA[xj];
            out_xt[t*131072 + (bsel ? bB : bA)*256 + xj] = xtv;

            const int sg = wvi, jg = lane;
            float aA[4] = {0.f, 0.f, 0.f, 0.f};
            float aB[4] = {0.f, 0.f, 0.f, 0.f};
            const uint4* xA = (const uint4*)xhA + sg*4;   // wave-uniform: broadcast reads
            const uint4* xB = (const uint4*)xhB + sg*4;
#pragma unroll
            for (int i = 0; i < 4; ++i) {
                uint4 ua = xA[i], ub = xB[i];
                H2U u0, u1, u2, u3, v0, v1, v2, v3;
                u0.u = ua.x; u1.u = ua.y; u2.u = ua.z; u3.u = ua.w;
                v0.u = ub.x; v1.u = ub.y; v2.u = ub.z; v3.u = ub.w;
#pragma unroll
                for (int jj = 0; jj < 4; ++jj) {
                    aA[jj] = fdot2(u0.h, wihr2[jj*16 + 4*i + 0], aA[jj]);
                    aA[jj] = fdot2(u1.h, wihr2[jj*16 + 4*i + 1], aA[jj]);
                    aA[jj] = fdot2(u2.h, wihr2[jj*16 + 4*i + 2], aA[jj]);
                    aA[jj] = fdot2(u3.h, wihr2[jj*16 + 4*i + 3], aA[jj]);
                    aB[jj] = fdot2(v0.h, wihr2[jj*16 + 4*i + 0], aB[jj]);
                    aB[jj] = fdot2(v1.h, wihr2[jj*16 + 4*i + 1], aB[jj]);
                    aB[jj] = fdot2(v2.h, wihr2[jj*16 + 4*i + 2], aB[jj]);
                    aB[jj] = fdot2(v3.h, wihr2[jj*16 + 4*i + 3], aB[jj]);
                }
            }
            // h-part fp32: k-slice [sg*8, +8) (wave-uniform broadcast reads of hc)
            float4 hA0 = *(const float4*)&hcA[sg*8];
            float4 hA1 = *(const float4*)&hcA[sg*8 + 4];
            float4 hB0 = *(const float4*)&hcB[sg*8];
            float4 hB1 = *(const float4*)&hcB[sg*8 + 4];
#pragma unroll
            for (int jj = 0; jj < 4; ++jj) {
                aA[jj] += hA0.x*whhr[jj*8+0] + hA0.y*whhr[jj*8+1] + hA0.z*whhr[jj*8+2] + hA0.w*whhr[jj*8+3]
                        + hA1.x*whhr[jj*8+4] + hA1.y*whhr[jj*8+5] + hA1.z*whhr[jj*8+6] + hA1.w*whhr[jj*8+7];
                aB[jj] += hB0.x*whhr[jj*8+0] + hB0.y*whhr[jj*8+1] + hB0.z*whhr[jj*8+2] + hB0.w*whhr[jj*8+3]
                        + hB1.x*whhr[jj*8+4] + hB1.y*whhr[jj*8+5] + hB1.z*whhr[jj*8+6] + hB1.w*whhr[jj*8+7];
            }
            psA[sg*256 + jg      ] = aA[0];
            psA[sg*256 + jg +  64] = aA[1];
            psA[sg*256 + jg + 128] = aA[2];
            psA[sg*256 + jg + 192] = aA[3];
            psB[sg*256 + jg      ] = aB[0];
            psB[sg*256 + jg +  64] = aB[1];
            psB[sg*256 + jg + 128] = aB[2];
            psB[sg*256 + jg + 192] = aB[3];
        }
        __syncthreads();   // B4

        // ---- P5: LSTM cell (wave0 = A, wave1 = B) ----
        if (wvi < 2) {
            float* ps = wvi ? psB : psA;
            float* hc = wvi ? hcB : hcA;
            float* oh = out_h + t*32768 + (wvi ? bB : bA)*64;
            const int k = lane;
            float gi = biasL[k], gf = biasL[64+k], gg = biasL[128+k], go = biasL[192+k];
#pragma unroll
            for (int s = 0; s < 8; ++s) {
                gi += ps[s*256 + k      ];
                gf += ps[s*256 + k +  64];
                gg += ps[s*256 + k + 128];
                go += ps[s*256 + k + 192];
            }
            gi = fsigmoid(gi); gf = fsigmoid(gf);
            gg = ftanh(gg);    go = fsigmoid(go);
            float cn = gf * hc[64 + k] + gi * gg;
            float hn = go * ftanh(cn);
            hc[k] = hn; hc[64 + k] = cn;
            oh[k] = hn;
        }
        __syncthreads();   // B5
    }
}

extern "C" void kernel_launch(void* const* d_in, const int* in_sizes, int n_in,
                              void* d_out, int out_size, void* d_ws, size_t ws_size,
                              hipStream_t stream) {
    const float* x    = (const float*)d_in[0];
    const float* w_ih = (const float*)d_in[1];
    const float* w_hh = (const float*)d_in[2];
    const float* b_ih = (const float*)d_in[3];
    const float* b_hh = (const float*)d_in[4];
    const float* w_v  = (const float*)d_in[5];
    const float* w_w  = (const float*)d_in[6];
    const float* b_w  = (const float*)d_in[7];
    const float* w_u  = (const float*)d_in[8];
    const float* b_u  = (const float*)d_in[9];

    float* out_xt = (float*)d_out;
    float* out_h  = out_xt + 64*512*256;

    const size_t shbytes = (size_t)L_TOT * sizeof(float);  // 161536 B
    (void)hipFuncSetAttribute((const void*)enc_kernel,
                        hipFuncAttributeMaxDynamicSharedMemorySize, (int)shbytes);
    enc_kernel<<<dim3(256), dim3(512), shbytes, stream>>>(
        x, w_ih, w_hh, b_ih, b_hh, w_v, w_w, b_w, w_u, b_u, out_xt, out_h);
}